// Round 1
// 1021.761 us; speedup vs baseline: 1.8143x; 1.8143x over previous
//
#include <hip/hip_runtime.h>
#include <math.h>

#define B_ 256
#define HID_ 512
#define H_ 8
#define D_ 64
#define FF_ 2048
#define L_ 6
#define EPS_ATTN 1e-6f
#define EPS_LN 1e-5f

typedef unsigned short u16;
typedef __attribute__((ext_vector_type(8))) short short8;
typedef __attribute__((ext_vector_type(4))) float floatx4;

__device__ inline u16 f2bf(float f) {
  union { float f; unsigned u; } un; un.f = f;
  unsigned u = un.u;
  u += 0x7FFFu + ((u >> 16) & 1u);   // RNE truncate to bf16
  return (u16)(u >> 16);
}

// ---------------- embedding + sinusoidal PE ----------------
__global__ __launch_bounds__(256) void embed_kernel(
    const int* __restrict__ x, const int* __restrict__ pos,
    const float* __restrict__ emb, float* __restrict__ h, u16* __restrict__ hb) {
  int b = blockIdx.x, t = threadIdx.x;
  int tok = x[b];
  float p = (float)pos[0];
  for (int i = t; i < HID_; i += 256) {
    int pair = i >> 1;
    float freq = powf(10000.f, -(float)pair * (1.f / 256.f));
    float ang = p * freq;
    float pe = (i & 1) ? cosf(ang) : sinf(ang);
    float v = emb[(size_t)tok * HID_ + i] + pe;
    h[b * HID_ + i] = v;
    hb[b * HID_ + i] = f2bf(v);
  }
}

// -------- weight convert: fp32 [K][N] -> bf16 WT [N][K], per layer ----------
// grid: (256, 6 matrices, n_layers); 64x64 tiles via LDS transpose
__global__ __launch_bounds__(256) void wconvert(
    const float* __restrict__ Wq, const float* __restrict__ Wk,
    const float* __restrict__ Wv, const float* __restrict__ Wo,
    const float* __restrict__ W1, const float* __restrict__ W2,
    u16* __restrict__ wt, int l0, size_t wt_stride) {
  int l = l0 + blockIdx.z;
  u16* dst = wt + (size_t)blockIdx.z * wt_stride;
  int mat = blockIdx.y;
  const float* src;
  int K, N;
  size_t doff;
  switch (mat) {
    case 0: src = Wq + (size_t)l * 262144; K = 512; N = 512; doff = 0; break;
    case 1: src = Wk + (size_t)l * 262144; K = 512; N = 512; doff = 262144; break;
    case 2: src = Wv + (size_t)l * 262144; K = 512; N = 512; doff = 524288; break;
    case 3: src = Wo + (size_t)l * 262144; K = 512; N = 512; doff = 786432; break;
    case 4: src = W1 + (size_t)l * 1048576; K = 512; N = 2048; doff = 1048576; break;
    default: src = W2 + (size_t)l * 1048576; K = 2048; N = 512; doff = 2097152; break;
  }
  int ntn = N >> 6;
  int ntiles = (K >> 6) * ntn;
  if (blockIdx.x >= ntiles) return;
  int tk = blockIdx.x / ntn, tn = blockIdx.x % ntn;
  __shared__ u16 sT[64][80];  // [n][k], pad 80 (160B rows, 16B-aligned)
  int t = threadIdx.x;
  int r = t >> 2, c = t & 3;
  const float* sp = src + (size_t)(tk * 64 + r) * N + tn * 64 + c * 16;
#pragma unroll
  for (int i = 0; i < 4; i++) {
    float4 v = *(const float4*)(sp + i * 4);
    int cb = c * 16 + i * 4;
    sT[cb + 0][r] = f2bf(v.x);
    sT[cb + 1][r] = f2bf(v.y);
    sT[cb + 2][r] = f2bf(v.z);
    sT[cb + 3][r] = f2bf(v.w);
  }
  __syncthreads();
  u16* dp = dst + doff + (size_t)(tn * 64 + r) * K + tk * 64 + c * 16;
  *(float4*)dp = *(const float4*)&sT[r][c * 16];
  *(float4*)(dp + 8) = *(const float4*)&sT[r][c * 16 + 8];
}

// ---------------- in-block split-K bf16 MFMA GEMM ---------------------------
// A bf16 [256][K], WT bf16 [N][K]. grid (N/64, 4). Block = 1024 thr = 16 waves
// = 4 M-subtiles x 4 K-quarters. Fragments loaded DIRECTLY from global (all
// operands are L2-resident); no LDS staging, no barriers in the K-loop.
// K-quarter partials reduced via padded LDS (single __syncthreads), epilogue
// done by the kg==0 waves. No global partials / counters / threadfences.
// mode 0: QKV (N=1536 logical -> qkv[3][256][512], elu+1 on q,k)
// mode 1: f32 out + bias
// mode 2: bf16 out + bias + relu
template <int NIT>
__global__ __launch_bounds__(1024, 1) void gemm_bk(
    const u16* __restrict__ A, const u16* __restrict__ WT,
    const float* __restrict__ b0, const float* __restrict__ b1,
    const float* __restrict__ b2, float* __restrict__ outf,
    u16* __restrict__ outb, int N, int K, int mode) {
  int t = threadIdx.x;
  int lane = t & 63, wv = t >> 6;
  int mg = wv & 3, kg = wv >> 2;       // M-subtile, K-quarter
  int m0 = blockIdx.y * 64, n0 = blockIdx.x * 64;
  int KQ = K >> 2;                      // == NIT*32
  const int lr = lane & 15, lk = lane >> 4;
  // identical lane->(row,k) fragment mapping as the verified LDS path:
  // A row = m0+mg*16+lr, k = kg*KQ + it*32 + lk*8
  const u16* ap = A + (size_t)(m0 + mg * 16 + lr) * K + kg * KQ + lk * 8;
  const u16* bp = WT + (size_t)(n0 + lr) * K + kg * KQ + lk * 8;
  floatx4 acc[4] = {};
#pragma unroll 2
  for (int it = 0; it < NIT; ++it) {
    short8 af = *(const short8*)(ap + it * 32);
#pragma unroll
    for (int nt = 0; nt < 4; nt++) {
      short8 bf = *(const short8*)(bp + (size_t)nt * 16 * K + it * 32);
      acc[nt] = __builtin_amdgcn_mfma_f32_16x16x32_bf16(af, bf, acc[nt], 0, 0, 0);
    }
  }
  // ---- in-block K reduction: kg 1..3 dump partials to LDS, kg 0 sums ----
  __shared__ float parts[3][64][68];   // pad 68: 16B-aligned rows, <=2-way banks
  if (kg > 0) {
#pragma unroll
    for (int nt = 0; nt < 4; nt++)
#pragma unroll
      for (int rr = 0; rr < 4; rr++)
        parts[kg - 1][mg * 16 + lk * 4 + rr][nt * 16 + lr] = acc[nt][rr];
  }
  __syncthreads();
  if (kg > 0) return;
#pragma unroll
  for (int nt = 0; nt < 4; nt++) {
#pragma unroll
    for (int rr = 0; rr < 4; rr++) {
      int row = mg * 16 + lk * 4 + rr;
      int col = nt * 16 + lr;
      float s = acc[nt][rr] + parts[0][row][col] + parts[1][row][col] +
                parts[2][row][col];
      int grow = m0 + row, gcol = n0 + col;
      if (mode == 0) {
        int sel = gcol >> 9, cc = gcol & 511;
        s += (sel == 0 ? b0 : sel == 1 ? b1 : b2)[cc];
        if (sel < 2) s = s > 0.f ? s + 1.f : expf(s);   // elu(x)+1
        outf[(size_t)sel * (B_ * HID_) + (size_t)grow * HID_ + cc] = s;
      } else if (mode == 1) {
        s += b0[gcol];
        outf[(size_t)grow * N + gcol] = s;
      } else {
        s += b0[gcol];
        outb[(size_t)grow * N + gcol] = f2bf(fmaxf(s, 0.f));
      }
    }
  }
}

// ---------------- linear-attention state update (HBM-bound) -----------------
__global__ __launch_bounds__(256) void state_kernel(
    const float* __restrict__ S_in, const float* __restrict__ Z_in,
    const float* __restrict__ qkv, float* __restrict__ S_out,
    float* __restrict__ Z_out, u16* __restrict__ attnb) {
  int bh = blockIdx.x;
  int b = bh >> 3, hh = bh & 7;
  const float* q = qkv + (size_t)b * HID_ + hh * D_;
  const float* k = q + (size_t)B_ * HID_;
  const float* v = q + (size_t)2 * B_ * HID_;
  __shared__ float qs[D_], ks[D_], vs[D_];
  __shared__ float part[16][D_];
  int t = threadIdx.x;
  if (t < D_) { qs[t] = q[t]; ks[t] = k[t]; vs[t] = v[t]; }
  __syncthreads();
  int tm = (t & 15) << 2;
  int rg = t >> 4;
  const float4* Sp = (const float4*)(S_in + (size_t)bh * D_ * D_);
  float4* So = (float4*)(S_out + (size_t)bh * D_ * D_);
  float4 vv = *(const float4*)(vs + tm);
  float4 acc = {0.f, 0.f, 0.f, 0.f};
#pragma unroll
  for (int i = 0; i < 4; i++) {
    int d = rg * 4 + i;
    float kd = ks[d], qd = qs[d];
    float4 s = Sp[(d * D_ + tm) >> 2];
    s.x += kd * vv.x; s.y += kd * vv.y; s.z += kd * vv.z; s.w += kd * vv.w;
    So[(d * D_ + tm) >> 2] = s;
    acc.x += qd * s.x; acc.y += qd * s.y; acc.z += qd * s.z; acc.w += qd * s.w;
  }
  *(float4*)(&part[rg][tm]) = acc;
  __syncthreads();
  if (t < D_) {
    float num = 0.f;
#pragma unroll
    for (int r = 0; r < 16; r++) num += part[r][t];
    float zk = Z_in[(size_t)bh * D_ + t] + ks[t];
    Z_out[(size_t)bh * D_ + t] = zk;
    float dv = qs[t] * zk;
#pragma unroll
    for (int off = 32; off > 0; off >>= 1) dv += __shfl_down(dv, off);
    float den = __shfl(dv, 0) + EPS_ATTN;
    attnb[(size_t)b * HID_ + hh * D_ + t] = f2bf(num / den);
  }
}

// ---------------- residual + LayerNorm --------------------------------------
__global__ __launch_bounds__(256) void ln_kernel(
    const float* __restrict__ x, const float* __restrict__ res,
    const float* __restrict__ g, const float* __restrict__ bb,
    float* __restrict__ out_f, u16* __restrict__ out_b) {
  int b = blockIdx.x, t = threadIdx.x;
  float v0 = x[b * HID_ + t] + (res ? res[b * HID_ + t] : 0.f);
  float v1 = x[b * HID_ + 256 + t] + (res ? res[b * HID_ + 256 + t] : 0.f);
  float s = v0 + v1, ss = v0 * v0 + v1 * v1;
#pragma unroll
  for (int off = 32; off > 0; off >>= 1) {
    s += __shfl_down(s, off);
    ss += __shfl_down(ss, off);
  }
  __shared__ float rs[4], rss[4];
  int w = t >> 6;
  if ((t & 63) == 0) { rs[w] = s; rss[w] = ss; }
  __syncthreads();
  float S = rs[0] + rs[1] + rs[2] + rs[3];
  float SS = rss[0] + rss[1] + rss[2] + rss[3];
  float mean = S * (1.f / HID_);
  float var = SS * (1.f / HID_) - mean * mean;
  float inv = rsqrtf(var + EPS_LN);
  float o0 = (v0 - mean) * inv * g[t] + bb[t];
  float o1 = (v1 - mean) * inv * g[256 + t] + bb[256 + t];
  out_f[b * HID_ + t] = o0;
  out_f[b * HID_ + 256 + t] = o1;
  if (out_b) {
    out_b[b * HID_ + t] = f2bf(o0);
    out_b[b * HID_ + 256 + t] = f2bf(o1);
  }
}

extern "C" void kernel_launch(void* const* d_in, const int* in_sizes, int n_in,
                              void* d_out, int out_size, void* d_ws, size_t ws_size,
                              hipStream_t stream) {
  const int* x = (const int*)d_in[0];
  const int* pos = (const int*)d_in[1];
  const float* S = (const float*)d_in[2];
  const float* Z = (const float*)d_in[3];
  const float* emb = (const float*)d_in[4];
  const float* Wq = (const float*)d_in[5];
  const float* bq = (const float*)d_in[6];
  const float* Wk = (const float*)d_in[7];
  const float* bk = (const float*)d_in[8];
  const float* Wv = (const float*)d_in[9];
  const float* bv = (const float*)d_in[10];
  const float* Wo = (const float*)d_in[11];
  const float* bo = (const float*)d_in[12];
  const float* W1 = (const float*)d_in[13];
  const float* b1 = (const float*)d_in[14];
  const float* W2 = (const float*)d_in[15];
  const float* b2 = (const float*)d_in[16];
  const float* ln1_g = (const float*)d_in[17];
  const float* ln1_b = (const float*)d_in[18];
  const float* ln2_g = (const float*)d_in[19];
  const float* ln2_b = (const float*)d_in[20];
  const float* lnf_g = (const float*)d_in[21];
  const float* lnf_b = (const float*)d_in[22];

  float* out_h = (float*)d_out;
  float* out_S = out_h + (size_t)B_ * HID_;
  float* out_Z = out_S + (size_t)L_ * B_ * H_ * D_ * D_;

  // ---- workspace layout (byte offsets; layout kept from prior version) ----
  char* w = (char*)d_ws;
  float* h     = (float*)(w + 0);          // 512 KB
  u16*   hb    = (u16*)(w + 524288);       // 256 KB
  u16*   attnb = (u16*)(w + 786432);       // 256 KB
  u16*   ff1   = (u16*)(w + 1048576);      // 1 MB
  float* qkv   = (float*)(w + 2097152);    // 1.5 MB
  float* tmpA  = (float*)(w + 3670016);    // 512 KB
  float* tmpB  = (float*)(w + 4194304);    // 512 KB
  u16*   wt    = (u16*)(w + 13109248);     // 6.29 MB/layer
  const size_t WT_LAYER = 3145728;         // u16 elements per layer
  bool bigws = ws_size >= (size_t)13109248 + WT_LAYER * 2 * L_;

  embed_kernel<<<B_, 256, 0, stream>>>(x, pos, emb, h, hb);
  if (bigws)
    wconvert<<<dim3(256, 6, L_), 256, 0, stream>>>(Wq, Wk, Wv, Wo, W1, W2,
                                                   wt, 0, WT_LAYER);
  for (int l = 0; l < L_; l++) {
    u16* wtl = bigws ? wt + (size_t)l * WT_LAYER : wt;
    if (!bigws)
      wconvert<<<dim3(256, 6, 1), 256, 0, stream>>>(Wq, Wk, Wv, Wo, W1, W2,
                                                    wtl, l, 0);
    // QKV: N=1536, K=512 (96 blocks x 1024 thr)
    gemm_bk<4><<<dim3(24, 4), 1024, 0, stream>>>(
        hb, wtl, bq + l * HID_, bk + l * HID_, bv + l * HID_,
        qkv, nullptr, 1536, 512, 0);
    state_kernel<<<B_ * H_, 256, 0, stream>>>(
        S + (size_t)l * B_ * H_ * D_ * D_, Z + (size_t)l * B_ * H_ * D_, qkv,
        out_S + (size_t)l * B_ * H_ * D_ * D_, out_Z + (size_t)l * B_ * H_ * D_,
        attnb);
    // Wo: N=512, K=512 (32 blocks)
    gemm_bk<4><<<dim3(8, 4), 1024, 0, stream>>>(
        attnb, wtl + 786432, bo + l * HID_, nullptr, nullptr,
        tmpA, nullptr, 512, 512, 1);
    ln_kernel<<<B_, 256, 0, stream>>>(tmpA, h, ln1_g + l * HID_, ln1_b + l * HID_, h, hb);
    // W1: N=2048, K=512 (128 blocks)
    gemm_bk<4><<<dim3(32, 4), 1024, 0, stream>>>(
        hb, wtl + 1048576, b1 + l * FF_, nullptr, nullptr,
        nullptr, ff1, 2048, 512, 2);
    // W2: N=512, K=2048 (32 blocks)
    gemm_bk<16><<<dim3(8, 4), 1024, 0, stream>>>(
        ff1, wtl + 2097152, b2 + l * HID_, nullptr, nullptr,
        tmpB, nullptr, 512, 2048, 1);
    ln_kernel<<<B_, 256, 0, stream>>>(tmpB, h, ln2_g + l * HID_, ln2_b + l * HID_, h, hb);
  }
  ln_kernel<<<B_, 256, 0, stream>>>(h, nullptr, lnf_g, lnf_b, out_h, nullptr);
}